// Round 5
// baseline (762.287 us; speedup 1.0000x reference)
//
#include <hip/hip_runtime.h>
#include <hip/hip_bf16.h>

typedef unsigned short u16;
typedef __attribute__((ext_vector_type(8))) short short8;
typedef __attribute__((ext_vector_type(4))) float floatx4;

#define HWPIX 16384
#define IMG 128

__device__ __forceinline__ float b2f(u16 u) {
    unsigned int x = ((unsigned int)u) << 16;
    return __builtin_bit_cast(float, x);
}
__device__ __forceinline__ u16 f2b(float f) {
    __hip_bfloat16 h = __float2bfloat16(f);
    return __builtin_bit_cast(u16, h);
}

// ---------------------------------------------------------------------------
// conv1x1: out[b][m][p] = act(scale * sum_c W[m][c] * X[c][p] + bias[m])
// IN_WS=1: X is bf16 from workspace (bws). IN_WS=0: X is fp32 external input
// (ein0 for c<256, ein1 for c>=256). W/bias fp32. Out bf16 (workspace).
// Tiles: M=64, N=128px, Kc=32.
// ---------------------------------------------------------------------------
template<int IN_WS>
__global__ __launch_bounds__(256)
void conv1x1_kernel(const float* __restrict__ ein0, const float* __restrict__ ein1,
                    const u16* __restrict__ bws,
                    const float* __restrict__ w, const float* __restrict__ bias,
                    u16* __restrict__ out, int K, float scale, int relu)
{
    __shared__ u16 Alds[64 * 40];   // [m][k] stride 40 (80B rows, 16B-aligned)
    __shared__ u16 Blds[128 * 40];  // [p][k] (transposed on write)

    const int tid = threadIdx.x;
    const int wave = tid >> 6, lane = tid & 63;
    const int quad = lane >> 4, l16 = lane & 15;
    const int pbase = blockIdx.x * 128;
    const int mbase = blockIdx.y * 64;
    const int b = blockIdx.z;

    floatx4 acc[8];
#pragma unroll
    for (int f = 0; f < 8; ++f) acc[f] = (floatx4){0.f, 0.f, 0.f, 0.f};

    const int a_r = tid >> 2, a_kg = tid & 3;     // A: 64 rows x 4 kgroups(8)
    const int b_ch = tid & 31, b_pg = tid >> 5;   // B: 32 ch x 8 pgroups(16)

    const int nchunk = K >> 5;
    for (int kc = 0; kc < nchunk; ++kc) {
        const int c0 = kc * 32;
        // ---- stage A (weights 64x32, fp32 -> bf16)
        {
            const float* wp = w + (size_t)(mbase + a_r) * K + c0 + a_kg * 8;
            float4 w0 = *(const float4*)wp;
            float4 w1 = *(const float4*)(wp + 4);
            union { uint4 v; u16 s[8]; } ta;
            ta.s[0] = f2b(w0.x); ta.s[1] = f2b(w0.y); ta.s[2] = f2b(w0.z); ta.s[3] = f2b(w0.w);
            ta.s[4] = f2b(w1.x); ta.s[5] = f2b(w1.y); ta.s[6] = f2b(w1.z); ta.s[7] = f2b(w1.w);
            *(uint4*)&Alds[a_r * 40 + a_kg * 8] = ta.v;
        }
        // ---- stage B (32ch x 128px), transpose to [p][c]
        {
            u16 vals[16];
            if (IN_WS) {
                const u16* src = bws + ((size_t)b * 256 + c0 + b_ch) * HWPIX + pbase + b_pg * 16;
                union { uint4 v[2]; u16 s[16]; } tb;
                tb.v[0] = *(const uint4*)src;
                tb.v[1] = *(const uint4*)(src + 8);
#pragma unroll
                for (int i = 0; i < 16; ++i) vals[i] = tb.s[i];
            } else {
                const int cc = c0 + b_ch;
                const float* base = (cc < 256) ? ein0 : ein1;
                const float* s = base + ((size_t)b * 256 + (cc & 255)) * HWPIX + pbase + b_pg * 16;
                float4 f0 = *(const float4*)s;
                float4 f1 = *(const float4*)(s + 4);
                float4 f2v = *(const float4*)(s + 8);
                float4 f3 = *(const float4*)(s + 12);
                float tmp[16] = {f0.x, f0.y, f0.z, f0.w, f1.x, f1.y, f1.z, f1.w,
                                 f2v.x, f2v.y, f2v.z, f2v.w, f3.x, f3.y, f3.z, f3.w};
#pragma unroll
                for (int i = 0; i < 16; ++i) vals[i] = f2b(tmp[i]);
            }
#pragma unroll
            for (int i = 0; i < 16; ++i)
                Blds[(b_pg * 16 + i) * 40 + b_ch] = vals[i];
        }
        __syncthreads();
        short8 afrag = *(const short8*)&Alds[(wave * 16 + l16) * 40 + quad * 8];
#pragma unroll
        for (int f = 0; f < 8; ++f) {
            short8 bfrag = *(const short8*)&Blds[(f * 16 + l16) * 40 + quad * 8];
            acc[f] = __builtin_amdgcn_mfma_f32_16x16x32_bf16(afrag, bfrag, acc[f], 0, 0, 0);
        }
        __syncthreads();
    }

    // epilogue: D[row=quad*4+r][col=l16]
    float bv[4];
#pragma unroll
    for (int r = 0; r < 4; ++r) {
        int m = mbase + wave * 16 + quad * 4 + r;
        bv[r] = bias ? bias[m] : 0.f;
    }
#pragma unroll
    for (int f = 0; f < 8; ++f) {
        int p = pbase + f * 16 + l16;
#pragma unroll
        for (int r = 0; r < 4; ++r) {
            int m = mbase + wave * 16 + quad * 4 + r;
            float v = acc[f][r] * scale + bv[r];
            if (relu) v = fmaxf(v, 0.f);
            out[((size_t)b * 256 + m) * HWPIX + p] = f2b(v);
        }
    }
}

// ---------------------------------------------------------------------------
// attention: one workgroup per (b, bh, bw, head). Q 64x64, K/V 196x64 (pad 224)
// q/k/v maps are bf16 workspace; rel tables fp32; OUTPUT IS FP32.
// ---------------------------------------------------------------------------
__global__ __launch_bounds__(256)
void attn_kernel(const u16* __restrict__ qmap, const u16* __restrict__ kmap,
                 const u16* __restrict__ vmap, const float* __restrict__ relh,
                 const float* __restrict__ relw, float* __restrict__ out)
{
    __shared__ u16 Qlds[64 * 72];    // [qpos][dd]; reused as O[dd][qpos]
    __shared__ u16 Klds[224 * 72];   // [kpos][dd]; reused as S[qpos][232]
    __shared__ u16 Vlds[64 * 232];   // V^T: [dd][kpos]

    const int tid = threadIdx.x;
    const int wave = tid >> 6, lane = tid & 63;
    const int quad = lane >> 4, l16 = lane & 15;
    const int bw = blockIdx.x, bh = blockIdx.y;
    const int b = blockIdx.z >> 2, head = blockIdx.z & 3;

    const size_t chbase = ((size_t)b * 256 + head * 64) * HWPIX;
    const int ih0 = bh * 8 - 3, iw0 = bw * 8 - 3;

    // ---- stage Q: [qpos][dd], qpos = r*8 + i
    for (int t = tid; t < 512; t += 256) {
        int ch = t >> 3, r = t & 7;
        union { uint4 v; u16 s[8]; } tq;
        tq.v = *(const uint4*)(qmap + chbase + ch * HWPIX + (bh * 8 + r) * IMG + bw * 8);
#pragma unroll
        for (int i = 0; i < 8; ++i) Qlds[(r * 8 + i) * 72 + ch] = tq.s[i];
    }
    // ---- stage K (+rel fp32) and V^T
    for (int t = tid; t < 896; t += 256) {
        int ch = t / 14, wr = t % 14;
        int ih = ih0 + wr;
        bool rok = (ih >= 0) && (ih < IMG);
        const u16* kp = kmap + chbase + ch * HWPIX + ih * IMG;
        const u16* vp = vmap + chbase + ch * HWPIX + ih * IMG;
        float rh = (ch < 32) ? relh[wr * 32 + ch] : 0.f;
#pragma unroll
        for (int wc = 0; wc < 14; ++wc) {
            int iw = iw0 + wc;
            bool ok = rok && (iw >= 0) && (iw < IMG);
            float kv = ok ? b2f(kp[iw]) : 0.f;
            float ra = (ch < 32) ? rh : relw[wc * 32 + (ch & 31)];
            Klds[(wr * 14 + wc) * 72 + ch] = f2b(kv + ra);
            Vlds[ch * 232 + wr * 14 + wc] = ok ? vp[iw] : (u16)0;
        }
    }
    // zero-pad kpos 196..223 (V must be 0 so attn 0 * pad != NaN)
    for (int t = tid; t < 28 * 64; t += 256) {
        int kp_ = 196 + (t >> 6), ch = t & 63;
        Klds[kp_ * 72 + ch] = 0;
        Vlds[ch * 232 + kp_] = 0;
    }
    __syncthreads();

    // ---- sim = Q K^T : wave strip 16(qpos) x 224(kpos)
    floatx4 sacc[14];
#pragma unroll
    for (int f = 0; f < 14; ++f) sacc[f] = (floatx4){0.f, 0.f, 0.f, 0.f};
#pragma unroll
    for (int kc = 0; kc < 2; ++kc) {
        short8 qa = *(const short8*)&Qlds[(wave * 16 + l16) * 72 + kc * 32 + quad * 8];
#pragma unroll
        for (int f = 0; f < 14; ++f) {
            short8 kb = *(const short8*)&Klds[(f * 16 + l16) * 72 + kc * 32 + quad * 8];
            sacc[f] = __builtin_amdgcn_mfma_f32_16x16x32_bf16(qa, kb, sacc[f], 0, 0, 0);
        }
    }

    // ---- softmax over kpos; row = quad*4+r, cols across f and l16
    float pm[14][4], rmax[4], rsum[4];
#pragma unroll
    for (int r = 0; r < 4; ++r) rmax[r] = -3.0e4f;
#pragma unroll
    for (int f = 0; f < 14; ++f) {
        int col = f * 16 + l16;
#pragma unroll
        for (int r = 0; r < 4; ++r) {
            float v = (col < 196) ? sacc[f][r] : -3.0e4f;
            pm[f][r] = v;
            rmax[r] = fmaxf(rmax[r], v);
        }
    }
#pragma unroll
    for (int off = 1; off < 16; off <<= 1)
#pragma unroll
        for (int r = 0; r < 4; ++r)
            rmax[r] = fmaxf(rmax[r], __shfl_xor(rmax[r], off, 64));
#pragma unroll
    for (int r = 0; r < 4; ++r) rsum[r] = 0.f;
#pragma unroll
    for (int f = 0; f < 14; ++f)
#pragma unroll
        for (int r = 0; r < 4; ++r) {
            float e = __expf(pm[f][r] - rmax[r]);
            pm[f][r] = e;
            rsum[r] += e;
        }
#pragma unroll
    for (int off = 1; off < 16; off <<= 1)
#pragma unroll
        for (int r = 0; r < 4; ++r)
            rsum[r] += __shfl_xor(rsum[r], off, 64);
    float rinv[4];
#pragma unroll
    for (int r = 0; r < 4; ++r) rinv[r] = 1.f / rsum[r];

    __syncthreads();  // all waves done reading Qlds/Klds

    // ---- P (bf16) into S = Klds region, [qpos][232]
    u16* S = Klds;
#pragma unroll
    for (int f = 0; f < 14; ++f)
#pragma unroll
        for (int r = 0; r < 4; ++r)
            S[(wave * 16 + quad * 4 + r) * 232 + f * 16 + l16] = f2b(pm[f][r] * rinv[r]);
    __syncthreads();

    // ---- out = P V : wave strip 16(qpos) x 64(dd), K = 224
    floatx4 oacc[4];
#pragma unroll
    for (int f = 0; f < 4; ++f) oacc[f] = (floatx4){0.f, 0.f, 0.f, 0.f};
#pragma unroll
    for (int kc = 0; kc < 7; ++kc) {
        short8 pa = *(const short8*)&S[(wave * 16 + l16) * 232 + kc * 32 + quad * 8];
#pragma unroll
        for (int f = 0; f < 4; ++f) {
            short8 vb = *(const short8*)&Vlds[(f * 16 + l16) * 232 + kc * 32 + quad * 8];
            oacc[f] = __builtin_amdgcn_mfma_f32_16x16x32_bf16(pa, vb, oacc[f], 0, 0, 0);
        }
    }

    // ---- transpose O through Qlds region (O[dd][qpos], stride 72)
    u16* O = Qlds;
#pragma unroll
    for (int f = 0; f < 4; ++f)
#pragma unroll
        for (int r = 0; r < 4; ++r)
            O[(f * 16 + l16) * 72 + wave * 16 + quad * 4 + r] = f2b(oacc[f][r]);
    __syncthreads();

    // ---- fp32 output stores (2x float4 per thread-iter)
    for (int t = tid; t < 512; t += 256) {
        int ch = t >> 3, r = t & 7;
        const u16* src = &O[ch * 72 + r * 8];
        float4 v0 = {b2f(src[0]), b2f(src[1]), b2f(src[2]), b2f(src[3])};
        float4 v1 = {b2f(src[4]), b2f(src[5]), b2f(src[6]), b2f(src[7])};
        float* dst = out + chbase + ch * HWPIX + (bh * 8 + r) * IMG + bw * 8;
        *(float4*)dst = v0;
        *(float4*)(dst + 4) = v1;
    }
}

extern "C" void kernel_launch(void* const* d_in, const int* in_sizes, int n_in,
                              void* d_out, int out_size, void* d_ws, size_t ws_size,
                              hipStream_t stream)
{
    (void)in_sizes; (void)n_in; (void)out_size; (void)ws_size;
    const float* noisy = (const float*)d_in[0];
    const float* aux   = (const float*)d_in[1];
    const float* w_map = (const float*)d_in[2];
    const float* b_map = (const float*)d_in[3];
    const float* w_q   = (const float*)d_in[4];
    const float* w_k   = (const float*)d_in[5];
    const float* w_v   = (const float*)d_in[6];
    const float* rel_h = (const float*)d_in[7];
    const float* rel_w = (const float*)d_in[8];
    float* out = (float*)d_out;

    // ws layout (96 MiB): [nv(naux->vmap) 32MiB][kmap 32MiB][qmap 32MiB]
    u16* nv   = (u16*)d_ws;
    u16* kmap = nv   + (size_t)16777216;
    u16* qmap = kmap + (size_t)16777216;

    dim3 cgrid(128, 4, 4);  // pixel tiles, m tiles, batch
    conv1x1_kernel<0><<<cgrid, 256, 0, stream>>>(noisy, aux, nullptr, w_map, b_map, nv,   512, 1.f,    1);
    conv1x1_kernel<1><<<cgrid, 256, 0, stream>>>(nullptr, nullptr, nv, w_q,  nullptr, qmap, 256, 0.125f, 0);
    conv1x1_kernel<1><<<cgrid, 256, 0, stream>>>(nullptr, nullptr, nv, w_k,  nullptr, kmap, 256, 1.f,    0);
    conv1x1_kernel<0><<<cgrid, 256, 0, stream>>>(noisy, noisy, nullptr, w_v, nullptr, nv,   256, 1.f,    0);
    attn_kernel<<<dim3(16, 16, 16), 256, 0, stream>>>(qmap, kmap, nv, rel_h, rel_w, out);
}

// Round 6
// 605.401 us; speedup vs baseline: 1.2591x; 1.2591x over previous
//
#include <hip/hip_runtime.h>
#include <hip/hip_bf16.h>

typedef unsigned short u16;
typedef __attribute__((ext_vector_type(8))) short short8;
typedef __attribute__((ext_vector_type(4))) float floatx4;

#define HWPIX 16384
#define IMG 128

__device__ __forceinline__ float b2f(u16 u) {
    unsigned int x = ((unsigned int)u) << 16;
    return __builtin_bit_cast(float, x);
}
__device__ __forceinline__ u16 f2b(float f) {
    __hip_bfloat16 h = __float2bfloat16(f);
    return __builtin_bit_cast(u16, h);
}

// ---------------------------------------------------------------------------
// conv1x1: out[b][m][p] = act(scale * sum_c W[m][c] * X[c][p] + bias[m])
// IN_WS=1: X bf16 workspace. IN_WS=0: X fp32 (ein0 c<256, ein1 c>=256).
// W/bias fp32; out bf16. Tiles M=64, N=128px, Kc=32. Software-pipelined:
// chunk k+1 global->regs overlaps MFMA on chunk k.
// ---------------------------------------------------------------------------
template<int IN_WS>
__global__ __launch_bounds__(256)
void conv1x1_kernel(const float* __restrict__ ein0, const float* __restrict__ ein1,
                    const u16* __restrict__ bws,
                    const float* __restrict__ w, const float* __restrict__ bias,
                    u16* __restrict__ out, int K, float scale, int relu)
{
    __shared__ u16 Alds[64 * 40];   // [m][k] stride 40
    __shared__ u16 Blds[128 * 40];  // [p][k]

    const int tid = threadIdx.x;
    const int wave = tid >> 6, lane = tid & 63;
    const int quad = lane >> 4, l16 = lane & 15;
    const int pbase = blockIdx.x * 128;
    const int mbase = blockIdx.y * 64;
    const int b = blockIdx.z;

    floatx4 acc[8];
#pragma unroll
    for (int f = 0; f < 8; ++f) acc[f] = (floatx4){0.f, 0.f, 0.f, 0.f};

    const int a_r = tid >> 2, a_kg = tid & 3;       // A: 64 rows x 4 kgroups(8)
    const int b_c4 = (tid & 7) * 4;                 // B: 8 ch-groups of 4
    const int b_p4 = (tid >> 3) * 4;                // B: 32 px-groups of 4

    // prefetch registers
    float4 af0, af1;
    float4 bfl[4];       // fp32 path: [ch_i] -> 4 px
    uint2  bbl[4];       // bf16 path: [ch_i] -> 4 px (4 u16)

    auto load_chunk = [&](int kc) {
        const int c0 = kc * 32;
        const float* wp = w + (size_t)(mbase + a_r) * K + c0 + a_kg * 8;
        af0 = *(const float4*)wp;
        af1 = *(const float4*)(wp + 4);
        if (IN_WS) {
#pragma unroll
            for (int i = 0; i < 4; ++i) {
                const u16* s = bws + ((size_t)b * 256 + c0 + b_c4 + i) * HWPIX + pbase + b_p4;
                bbl[i] = *(const uint2*)s;
            }
        } else {
            const float* base = (c0 < 256) ? ein0 : ein1;
            const int cb = c0 & 255;
#pragma unroll
            for (int i = 0; i < 4; ++i) {
                const float* s = base + ((size_t)b * 256 + cb + b_c4 + i) * HWPIX + pbase + b_p4;
                bfl[i] = *(const float4*)s;
            }
        }
    };
    auto write_chunk = [&]() {
        union { uint4 v; u16 s[8]; } ta;
        ta.s[0] = f2b(af0.x); ta.s[1] = f2b(af0.y); ta.s[2] = f2b(af0.z); ta.s[3] = f2b(af0.w);
        ta.s[4] = f2b(af1.x); ta.s[5] = f2b(af1.y); ta.s[6] = f2b(af1.z); ta.s[7] = f2b(af1.w);
        *(uint4*)&Alds[a_r * 40 + a_kg * 8] = ta.v;
        if (IN_WS) {
            union { uint2 v; u16 s[4]; } c[4];
#pragma unroll
            for (int i = 0; i < 4; ++i) c[i].v = bbl[i];
#pragma unroll
            for (int j = 0; j < 4; ++j) {
                union { uint2 v; u16 s[4]; } o;
#pragma unroll
                for (int i = 0; i < 4; ++i) o.s[i] = c[i].s[j];
                *(uint2*)&Blds[(b_p4 + j) * 40 + b_c4] = o.v;
            }
        } else {
            float px[4][4];
#pragma unroll
            for (int i = 0; i < 4; ++i) {
                px[i][0] = bfl[i].x; px[i][1] = bfl[i].y; px[i][2] = bfl[i].z; px[i][3] = bfl[i].w;
            }
#pragma unroll
            for (int j = 0; j < 4; ++j) {
                union { uint2 v; u16 s[4]; } o;
#pragma unroll
                for (int i = 0; i < 4; ++i) o.s[i] = f2b(px[i][j]);
                *(uint2*)&Blds[(b_p4 + j) * 40 + b_c4] = o.v;
            }
        }
    };

    const int nchunk = K >> 5;
    load_chunk(0);
    for (int kc = 0; kc < nchunk; ++kc) {
        if (kc) __syncthreads();           // prev MFMA done reading LDS
        write_chunk();
        __syncthreads();
        if (kc + 1 < nchunk) load_chunk(kc + 1);   // overlaps MFMA below
        short8 afrag = *(const short8*)&Alds[(wave * 16 + l16) * 40 + quad * 8];
#pragma unroll
        for (int f = 0; f < 8; ++f) {
            short8 bfrag = *(const short8*)&Blds[(f * 16 + l16) * 40 + quad * 8];
            acc[f] = __builtin_amdgcn_mfma_f32_16x16x32_bf16(afrag, bfrag, acc[f], 0, 0, 0);
        }
    }

    // epilogue: D[row=quad*4+r][col=l16]
    float bv[4];
#pragma unroll
    for (int r = 0; r < 4; ++r) {
        int m = mbase + wave * 16 + quad * 4 + r;
        bv[r] = bias ? bias[m] : 0.f;
    }
#pragma unroll
    for (int f = 0; f < 8; ++f) {
        int p = pbase + f * 16 + l16;
#pragma unroll
        for (int r = 0; r < 4; ++r) {
            int m = mbase + wave * 16 + quad * 4 + r;
            float v = acc[f][r] * scale + bv[r];
            if (relu) v = fmaxf(v, 0.f);
            out[((size_t)b * 256 + m) * HWPIX + p] = f2b(v);
        }
    }
}

// ---------------------------------------------------------------------------
// attention: one workgroup per (b, bh, bw, head). Q 64x64, K/V 196x64 (pad 224)
// Branch-free pipelined K/V staging: tid -> (window row, col), 64-ch loop of
// independent clamped loads + cndmask. Rel tables pre-staged in LDS.
// ---------------------------------------------------------------------------
__global__ __launch_bounds__(256)
void attn_kernel(const u16* __restrict__ qmap, const u16* __restrict__ kmap,
                 const u16* __restrict__ vmap, const float* __restrict__ relh,
                 const float* __restrict__ relw, float* __restrict__ out)
{
    __shared__ u16 Qlds[64 * 72];    // [qpos][dd]; reused as O[dd][qpos]
    __shared__ u16 Klds[224 * 72];   // [kpos][dd]; reused as S[qpos][232]
    __shared__ u16 Vlds[64 * 232];   // V^T: [dd][kpos]
    __shared__ float RelHf[448], RelWf[448];

    const int tid = threadIdx.x;
    const int wave = tid >> 6, lane = tid & 63;
    const int quad = lane >> 4, l16 = lane & 15;
    const int bw = blockIdx.x, bh = blockIdx.y;
    const int b = blockIdx.z >> 2, head = blockIdx.z & 3;

    const size_t chbase = ((size_t)b * 256 + head * 64) * HWPIX;
    const int ih0 = bh * 8 - 3, iw0 = bw * 8 - 3;

    // ---- rel tables -> LDS
    for (int t = tid; t < 448; t += 256) {
        RelHf[t] = relh[t];
        RelWf[t] = relw[t];
    }
    // ---- stage Q: [qpos][dd], qpos = r*8 + i
    for (int t = tid; t < 512; t += 256) {
        int ch = t >> 3, r = t & 7;
        union { uint4 v; u16 s[8]; } tq;
        tq.v = *(const uint4*)(qmap + chbase + ch * HWPIX + (bh * 8 + r) * IMG + bw * 8);
#pragma unroll
        for (int i = 0; i < 8; ++i) Qlds[(r * 8 + i) * 72 + ch] = tq.s[i];
    }
    __syncthreads();   // RelHf/RelWf visible before the KV loop reads them

    // ---- stage K (+rel) and V^T: tid -> (wr 0..13, sc 0..15), 224 active
    if (tid < 224) {
        const int wr = tid >> 4, sc = tid & 15;
        const int ih = ih0 + wr, iw = iw0 + sc;
        const bool wok = sc < 14;
        const bool ok = wok && ((unsigned)ih < 128u) && ((unsigned)iw < 128u);
        const int ihc = min(max(ih, 0), 127), iwc = min(max(iw, 0), 127);
        const int kpos = wr * 14 + sc;
        const u16* kp = kmap + chbase + ihc * IMG + iwc;
        const u16* vp = vmap + chbase + ihc * IMG + iwc;
#pragma unroll 4
        for (int ch = 0; ch < 64; ++ch) {
            u16 kraw = kp[(size_t)ch * HWPIX];
            u16 vraw = vp[(size_t)ch * HWPIX];
            float kv = ok ? b2f(kraw) : 0.f;
            float rel = (ch < 32) ? RelHf[wr * 32 + ch] : RelWf[sc * 32 + (ch - 32)];
            if (wok) {
                Klds[kpos * 72 + ch] = f2b(kv + rel);
                Vlds[ch * 232 + kpos] = ok ? vraw : (u16)0;
            }
        }
    }
    // zero-pad kpos 196..223 (V must be 0 so attn 0 * pad != NaN)
    for (int t = tid; t < 28 * 64; t += 256) {
        int kp_ = 196 + (t >> 6), ch = t & 63;
        Klds[kp_ * 72 + ch] = 0;
        Vlds[ch * 232 + kp_] = 0;
    }
    __syncthreads();

    // ---- sim = Q K^T : wave strip 16(qpos) x 224(kpos)
    floatx4 sacc[14];
#pragma unroll
    for (int f = 0; f < 14; ++f) sacc[f] = (floatx4){0.f, 0.f, 0.f, 0.f};
#pragma unroll
    for (int kc = 0; kc < 2; ++kc) {
        short8 qa = *(const short8*)&Qlds[(wave * 16 + l16) * 72 + kc * 32 + quad * 8];
#pragma unroll
        for (int f = 0; f < 14; ++f) {
            short8 kb = *(const short8*)&Klds[(f * 16 + l16) * 72 + kc * 32 + quad * 8];
            sacc[f] = __builtin_amdgcn_mfma_f32_16x16x32_bf16(qa, kb, sacc[f], 0, 0, 0);
        }
    }

    // ---- softmax over kpos; row = quad*4+r
    float pm[14][4], rmax[4], rsum[4];
#pragma unroll
    for (int r = 0; r < 4; ++r) rmax[r] = -3.0e4f;
#pragma unroll
    for (int f = 0; f < 14; ++f) {
        int col = f * 16 + l16;
#pragma unroll
        for (int r = 0; r < 4; ++r) {
            float v = (col < 196) ? sacc[f][r] : -3.0e4f;
            pm[f][r] = v;
            rmax[r] = fmaxf(rmax[r], v);
        }
    }
#pragma unroll
    for (int off = 1; off < 16; off <<= 1)
#pragma unroll
        for (int r = 0; r < 4; ++r)
            rmax[r] = fmaxf(rmax[r], __shfl_xor(rmax[r], off, 64));
#pragma unroll
    for (int r = 0; r < 4; ++r) rsum[r] = 0.f;
#pragma unroll
    for (int f = 0; f < 14; ++f)
#pragma unroll
        for (int r = 0; r < 4; ++r) {
            float e = __expf(pm[f][r] - rmax[r]);
            pm[f][r] = e;
            rsum[r] += e;
        }
#pragma unroll
    for (int off = 1; off < 16; off <<= 1)
#pragma unroll
        for (int r = 0; r < 4; ++r)
            rsum[r] += __shfl_xor(rsum[r], off, 64);
    float rinv[4];
#pragma unroll
    for (int r = 0; r < 4; ++r) rinv[r] = 1.f / rsum[r];

    __syncthreads();  // all waves done reading Qlds/Klds

    // ---- P (bf16) into S = Klds region, [qpos][232]
    u16* S = Klds;
#pragma unroll
    for (int f = 0; f < 14; ++f)
#pragma unroll
        for (int r = 0; r < 4; ++r)
            S[(wave * 16 + quad * 4 + r) * 232 + f * 16 + l16] = f2b(pm[f][r] * rinv[r]);
    __syncthreads();

    // ---- out = P V : wave strip 16(qpos) x 64(dd), K = 224
    floatx4 oacc[4];
#pragma unroll
    for (int f = 0; f < 4; ++f) oacc[f] = (floatx4){0.f, 0.f, 0.f, 0.f};
#pragma unroll
    for (int kc = 0; kc < 7; ++kc) {
        short8 pa = *(const short8*)&S[(wave * 16 + l16) * 232 + kc * 32 + quad * 8];
#pragma unroll
        for (int f = 0; f < 4; ++f) {
            short8 vb = *(const short8*)&Vlds[(f * 16 + l16) * 232 + kc * 32 + quad * 8];
            oacc[f] = __builtin_amdgcn_mfma_f32_16x16x32_bf16(pa, vb, oacc[f], 0, 0, 0);
        }
    }

    // ---- transpose O through Qlds region (O[dd][qpos], stride 72)
    u16* O = Qlds;
#pragma unroll
    for (int f = 0; f < 4; ++f)
#pragma unroll
        for (int r = 0; r < 4; ++r)
            O[(f * 16 + l16) * 72 + wave * 16 + quad * 4 + r] = f2b(oacc[f][r]);
    __syncthreads();

    // ---- fp32 output stores
    for (int t = tid; t < 512; t += 256) {
        int ch = t >> 3, r = t & 7;
        const u16* src = &O[ch * 72 + r * 8];
        float4 v0 = {b2f(src[0]), b2f(src[1]), b2f(src[2]), b2f(src[3])};
        float4 v1 = {b2f(src[4]), b2f(src[5]), b2f(src[6]), b2f(src[7])};
        float* dst = out + chbase + ch * HWPIX + (bh * 8 + r) * IMG + bw * 8;
        *(float4*)dst = v0;
        *(float4*)(dst + 4) = v1;
    }
}

extern "C" void kernel_launch(void* const* d_in, const int* in_sizes, int n_in,
                              void* d_out, int out_size, void* d_ws, size_t ws_size,
                              hipStream_t stream)
{
    (void)in_sizes; (void)n_in; (void)out_size; (void)ws_size;
    const float* noisy = (const float*)d_in[0];
    const float* aux   = (const float*)d_in[1];
    const float* w_map = (const float*)d_in[2];
    const float* b_map = (const float*)d_in[3];
    const float* w_q   = (const float*)d_in[4];
    const float* w_k   = (const float*)d_in[5];
    const float* w_v   = (const float*)d_in[6];
    const float* rel_h = (const float*)d_in[7];
    const float* rel_w = (const float*)d_in[8];
    float* out = (float*)d_out;

    // ws layout (96 MiB): [nv(naux->vmap) 32MiB][kmap 32MiB][qmap 32MiB]
    u16* nv   = (u16*)d_ws;
    u16* kmap = nv   + (size_t)16777216;
    u16* qmap = kmap + (size_t)16777216;

    dim3 cgrid(128, 4, 4);  // pixel tiles, m tiles, batch
    conv1x1_kernel<0><<<cgrid, 256, 0, stream>>>(noisy, aux, nullptr, w_map, b_map, nv,   512, 1.f,    1);
    conv1x1_kernel<1><<<cgrid, 256, 0, stream>>>(nullptr, nullptr, nv, w_q,  nullptr, qmap, 256, 0.125f, 0);
    conv1x1_kernel<1><<<cgrid, 256, 0, stream>>>(nullptr, nullptr, nv, w_k,  nullptr, kmap, 256, 1.f,    0);
    conv1x1_kernel<0><<<cgrid, 256, 0, stream>>>(noisy, noisy, nullptr, w_v, nullptr, nv,   256, 1.f,    0);
    attn_kernel<<<dim3(16, 16, 16), 256, 0, stream>>>(qmap, kmap, nv, rel_h, rel_w, out);
}